// Round 4
// baseline (474.247 us; speedup 1.0000x reference)
//
#include <hip/hip_runtime.h>
#include <math.h>

// PillarAttentionClassifier — R5: R2-exact datapath (proven correct) + safe
// latency cuts only:
//   * x load software-pipelined one tile ahead (same data, same bits).
//   * stage-2 A-frags (3x ds_read_b128 of repT) kept in regs, reused by
//     stage-3 (R2 re-read the same bytes — bit-identical).
//   * 16 tiles/block -> 2048 blocks; __launch_bounds__(256,3).
// LDS scheme, layouts, and all arithmetic are exactly R2 (absmax 0.0039).
// tr-read experiment (R3/R4) abandoned: deterministic 0.0488 absmax with
// identical error under RTE vs RTZ => transpose-path data mismatch.

typedef _Float16 f16x8 __attribute__((ext_vector_type(8)));
typedef float    f32x4 __attribute__((ext_vector_type(4)));

#define EPS 1e-5f

__device__ __forceinline__ float rcp_fast(float v) { return __builtin_amdgcn_rcpf(v); }

__host__ __device__ constexpr unsigned long long packGS() {
    constexpr int gs[12] = {0,3,5,7,10,12,15,17,19,20,23,26};
    unsigned long long v = 0;
    for (int g = 0; g < 12; ++g) v |= (unsigned long long)gs[g] << (5*g);
    return v;
}
__host__ __device__ constexpr unsigned packGL() {
    constexpr int gl[12] = {3,2,2,3,2,3,2,2,1,3,3,3};
    unsigned v = 0;
    for (int g = 0; g < 12; ++g) v |= (unsigned)gl[g] << (2*g);
    return v;
}

__global__ __launch_bounds__(256, 3) void fused_kernel(
    const float* __restrict__ x,
    const float* __restrict__ We,  const float* __restrict__ be,
    const float* __restrict__ eg,  const float* __restrict__ ebt,
    const float* __restrict__ em,  const float* __restrict__ ev,
    const float* __restrict__ Wa,  const float* __restrict__ ba,
    const float* __restrict__ W1,  const float* __restrict__ b1,
    const float* __restrict__ g1,  const float* __restrict__ bb1,
    const float* __restrict__ m1,  const float* __restrict__ v1,
    const float* __restrict__ W2,  const float* __restrict__ b2,
    const float* __restrict__ g2,  const float* __restrict__ bb2,
    const float* __restrict__ m2,  const float* __restrict__ v2,
    const float* __restrict__ W3,  const float* __restrict__ b3,
    const float* __restrict__ g3,  const float* __restrict__ bb3,
    const float* __restrict__ m3,  const float* __restrict__ v3,
    const float* __restrict__ W4,  const float* __restrict__ b4,
    float* __restrict__ out, int B, int ntiles)
{
    // per-wave private LDS scratch: 8192 B each, 4 waves = 32 KiB (R2 layout)
    __shared__ __align__(16) char smem_raw[32768];
    const int lane = threadIdx.x & 63;
    const int wave = threadIdx.x >> 6;
    const int l15  = lane & 15;
    const int quad = lane >> 4;

    char* sw = smem_raw + wave * 8192;
    _Float16* repT = (_Float16*)(sw);          // [16][104] f16
    float*    wT   = (float*)   (sw + 3328);   // [16][17]  f32
    _Float16* h1T  = (_Float16*)(sw + 4416);   // [16][72]  f16
    _Float16* h2T  = (_Float16*)(sw + 6720);   // [16][40]  f16

    constexpr unsigned long long GS = packGS();
    constexpr unsigned GL = packGL();

    // ================= per-block prologue: B-frags + params (L2-resident) ========
    f16x8 Benc[6];
    #pragma unroll
    for (int t = 0; t < 6; ++t) {
        const int n = t*16 + l15;
        const int g = n >> 3, o = n & 7;
        const int gs = (int)((GS >> (5*g)) & 31);
        const int gl = (int)((GL >> (2*g)) & 3);
        #pragma unroll
        for (int j = 0; j < 8; ++j) {
            const int k  = quad*8 + j;
            const int ji = k - gs;
            float v = (ji >= 0 && ji < gl) ? We[(g*3 + ji)*8 + o] : 0.f;
            Benc[t][j] = (_Float16)v;
        }
    }
    f16x8 Bwa[3];
    #pragma unroll
    for (int s = 0; s < 3; ++s) {
        #pragma unroll
        for (int j = 0; j < 8; ++j) {
            const int k = s*32 + quad*8 + j;
            float v = (l15 < 12) ? Wa[k*12 + l15] : 0.f;
            Bwa[s][j] = (_Float16)v;
        }
    }
    f16x8 Bw1[12];
    #pragma unroll
    for (int t = 0; t < 4; ++t)
        #pragma unroll
        for (int s = 0; s < 3; ++s)
            #pragma unroll
            for (int j = 0; j < 8; ++j) {
                const int k = s*32 + quad*8 + j;
                Bw1[t*3 + s][j] = (_Float16)W1[k*64 + t*16 + l15];
            }
    f16x8 Bw2[4];
    #pragma unroll
    for (int t = 0; t < 2; ++t)
        #pragma unroll
        for (int s = 0; s < 2; ++s)
            #pragma unroll
            for (int j = 0; j < 8; ++j) {
                const int k = s*32 + quad*8 + j;
                Bw2[t*2 + s][j] = (_Float16)W2[k*32 + t*16 + l15];
            }
    f16x8 Bw3;
    #pragma unroll
    for (int j = 0; j < 8; ++j)
        Bw3[j] = (_Float16)W3[(quad*8 + j)*16 + l15];

    // per-lane params (indexed by output col n = lane&15 within each 16-block)
    float encB[6], encS[6], encT[6];
    #pragma unroll
    for (int t = 0; t < 6; ++t) {
        const int c = t*16 + l15;
        float s = eg[c] * rsqrtf(ev[c] + EPS);
        encS[t] = s; encT[t] = ebt[c] - em[c]*s; encB[t] = be[c];
    }
    const float baL = (l15 < 12) ? ba[l15] : -1e4f;   // pad cols -> softmax weight 0
    float b1L[4], s1L[4], t1L[4];
    #pragma unroll
    for (int t = 0; t < 4; ++t) {
        const int c = t*16 + l15;
        float s = g1[c] * rsqrtf(v1[c] + EPS);
        s1L[t] = s; t1L[t] = bb1[c] - m1[c]*s; b1L[t] = b1[c];
    }
    float b2L[2], s2L[2], t2L[2];
    #pragma unroll
    for (int t = 0; t < 2; ++t) {
        const int c = t*16 + l15;
        float s = g2[c] * rsqrtf(v2[c] + EPS);
        s2L[t] = s; t2L[t] = bb2[c] - m2[c]*s; b2L[t] = b2[c];
    }
    const float sv3 = g3[l15] * rsqrtf(v3[l15] + EPS);
    const float b3L = b3[l15], s3L = sv3, t3L = bb3[l15] - m3[l15]*sv3;
    const float w4L = W4[l15];
    const float b4v = b4[0];

    // ================= main loop: 16 tiles/block, 4/wave, x prefetched ===========
    const int tile0 = blockIdx.x * 16;
    int tile1 = tile0 + 16; if (tile1 > ntiles) tile1 = ntiles;

    auto load_x = [&](int t, float* d) {
        const int rb = t << 4;
        int xr = rb + l15; if (xr > B-1) xr = B-1;
        const float* xp = x + (size_t)xr*29 + (quad<<3);
        if (quad < 3) {
            #pragma unroll
            for (int j = 0; j < 8; ++j) d[j] = xp[j];
        } else {
            #pragma unroll
            for (int j = 0; j < 5; ++j) d[j] = xp[j];
            d[5] = d[6] = d[7] = 0.f;
        }
    };

    float xv[8];
    int tile = tile0 + wave;
    if (tile < tile1) load_x(tile, xv);

    for (; tile < tile1; tile += 4) {
        const int rowbase = tile << 4;

        // ---- prefetch next tile's x (overlaps with this tile's compute) ----
        float xn[8];
        {
            int nt = tile + 4;
            load_x(nt < tile1 ? nt : tile, xn);
        }

        // ---- x A-frag: A[m=l15][k=quad*8+j] ----
        f16x8 ax;
        #pragma unroll
        for (int j = 0; j < 8; ++j) ax[j] = (_Float16)xv[j];

        // ---- stage 1: rep[16][96] = BNaff(relu(x @ Wenc + be)) ----
        #pragma unroll
        for (int t = 0; t < 6; ++t) {
            f32x4 c = { encB[t], encB[t], encB[t], encB[t] };
            c = __builtin_amdgcn_mfma_f32_16x16x32_f16(ax, Benc[t], c, 0, 0, 0);
            #pragma unroll
            for (int r = 0; r < 4; ++r) {
                float v = fmaf(fmaxf(c[r], 0.f), encS[t], encT[t]);
                repT[(quad*4 + r)*104 + t*16 + l15] = (_Float16)v;
            }
        }

        // ---- read rep A-frags once; reused by stage 2 AND stage 3 ----
        f16x8 aS[3];
        #pragma unroll
        for (int s = 0; s < 3; ++s)
            aS[s] = *(const f16x8*)(repT + l15*104 + s*32 + quad*8);

        // ---- stage 2: logits = rep @ Wa + ba ; softmax over 12 (per quad) ----
        f32x4 c2 = { baL, baL, baL, baL };
        #pragma unroll
        for (int s = 0; s < 3; ++s)
            c2 = __builtin_amdgcn_mfma_f32_16x16x32_f16(aS[s], Bwa[s], c2, 0, 0, 0);
        #pragma unroll
        for (int r = 0; r < 4; ++r) {
            float v = c2[r];
            float mx = v;
            mx = fmaxf(mx, __shfl_xor(mx, 1));
            mx = fmaxf(mx, __shfl_xor(mx, 2));
            mx = fmaxf(mx, __shfl_xor(mx, 4));
            mx = fmaxf(mx, __shfl_xor(mx, 8));
            float e = __expf(v - mx);
            float sm = e;
            sm += __shfl_xor(sm, 1);
            sm += __shfl_xor(sm, 2);
            sm += __shfl_xor(sm, 4);
            sm += __shfl_xor(sm, 8);
            wT[(quad*4 + r)*17 + l15] = e * rcp_fast(sm);
        }

        // ---- stage 3: h1 = BNaff(relu((rep .* w_group) @ W1 + b1)) ----
        // A-frag k-range s*32+quad*8..+7 -> group g = s*4+quad constant per frag
        f32x4 c3[4];
        #pragma unroll
        for (int t = 0; t < 4; ++t) c3[t] = { b1L[t], b1L[t], b1L[t], b1L[t] };
        #pragma unroll
        for (int s = 0; s < 3; ++s) {
            _Float16 wh = (_Float16)wT[l15*17 + s*4 + quad];
            f16x8 aw;
            #pragma unroll
            for (int j = 0; j < 8; ++j) aw[j] = aS[s][j] * wh;
            #pragma unroll
            for (int t = 0; t < 4; ++t)
                c3[t] = __builtin_amdgcn_mfma_f32_16x16x32_f16(aw, Bw1[t*3 + s], c3[t], 0, 0, 0);
        }
        #pragma unroll
        for (int t = 0; t < 4; ++t)
            #pragma unroll
            for (int r = 0; r < 4; ++r) {
                float v = fmaf(fmaxf(c3[t][r], 0.f), s1L[t], t1L[t]);
                h1T[(quad*4 + r)*72 + t*16 + l15] = (_Float16)v;
            }

        // ---- stage 4: h2 = BNaff(relu(h1 @ W2 + b2)) ----
        f32x4 c4[2];
        #pragma unroll
        for (int t = 0; t < 2; ++t) c4[t] = { b2L[t], b2L[t], b2L[t], b2L[t] };
        #pragma unroll
        for (int s = 0; s < 2; ++s) {
            f16x8 a = *(const f16x8*)(h1T + l15*72 + s*32 + quad*8);
            #pragma unroll
            for (int t = 0; t < 2; ++t)
                c4[t] = __builtin_amdgcn_mfma_f32_16x16x32_f16(a, Bw2[t*2 + s], c4[t], 0, 0, 0);
        }
        #pragma unroll
        for (int t = 0; t < 2; ++t)
            #pragma unroll
            for (int r = 0; r < 4; ++r) {
                float v = fmaf(fmaxf(c4[t][r], 0.f), s2L[t], t2L[t]);
                h2T[(quad*4 + r)*40 + t*16 + l15] = (_Float16)v;
            }

        // ---- stage 5: h3 = BNaff(relu(h2 @ W3 + b3)) (stays in regs) ----
        f32x4 c5 = { b3L, b3L, b3L, b3L };
        {
            f16x8 a = *(const f16x8*)(h2T + l15*40 + quad*8);
            c5 = __builtin_amdgcn_mfma_f32_16x16x32_f16(a, Bw3, c5, 0, 0, 0);
        }

        // ---- stage 6: z = h3 @ W4 + b4 ; sigmoid ; store ----
        float z[4];
        #pragma unroll
        for (int r = 0; r < 4; ++r) {
            float v = fmaf(fmaxf(c5[r], 0.f), s3L, t3L);
            float p = v * w4L;
            p += __shfl_xor(p, 1);
            p += __shfl_xor(p, 2);
            p += __shfl_xor(p, 4);
            p += __shfl_xor(p, 8);
            z[r] = p;
        }
        float zi = (l15 == 0) ? z[0] : (l15 == 1) ? z[1] : (l15 == 2) ? z[2] : z[3];
        if (l15 < 4) {
            int row = rowbase + quad*4 + l15;
            if (row < B)
                out[row] = rcp_fast(1.f + __expf(-(zi + b4v)));
        }

        // ---- rotate prefetch ----
        #pragma unroll
        for (int j = 0; j < 8; ++j) xv[j] = xn[j];
    }
}

extern "C" void kernel_launch(void* const* d_in, const int* in_sizes, int n_in,
                              void* d_out, int out_size, void* d_ws, size_t ws_size,
                              hipStream_t stream)
{
    const float* x   = (const float*)d_in[0];
    const float* We  = (const float*)d_in[1];
    const float* be  = (const float*)d_in[2];
    const float* eg  = (const float*)d_in[3];
    const float* ebt = (const float*)d_in[4];
    const float* em  = (const float*)d_in[5];
    const float* ev  = (const float*)d_in[6];
    const float* Wa  = (const float*)d_in[7];
    const float* ba  = (const float*)d_in[8];
    const float* W1  = (const float*)d_in[9];
    const float* b1  = (const float*)d_in[10];
    const float* g1  = (const float*)d_in[11];
    const float* bb1 = (const float*)d_in[12];
    const float* m1  = (const float*)d_in[13];
    const float* v1  = (const float*)d_in[14];
    const float* W2  = (const float*)d_in[15];
    const float* b2  = (const float*)d_in[16];
    const float* g2  = (const float*)d_in[17];
    const float* bb2 = (const float*)d_in[18];
    const float* m2  = (const float*)d_in[19];
    const float* v2  = (const float*)d_in[20];
    const float* W3  = (const float*)d_in[21];
    const float* b3  = (const float*)d_in[22];
    const float* g3  = (const float*)d_in[23];
    const float* bb3 = (const float*)d_in[24];
    const float* m3  = (const float*)d_in[25];
    const float* v3  = (const float*)d_in[26];
    const float* W4  = (const float*)d_in[27];
    const float* b4  = (const float*)d_in[28];

    const int B = in_sizes[0] / 29;
    const int ntiles = (B + 15) / 16;
    const int blocks = (ntiles + 15) / 16;   // 16 tiles per block (4 per wave)

    fused_kernel<<<blocks, 256, 0, stream>>>(
        x, We, be, eg, ebt, em, ev, Wa, ba,
        W1, b1, g1, bb1, m1, v1,
        W2, b2, g2, bb2, m2, v2,
        W3, b3, g3, bb3, m3, v3,
        W4, b4, (float*)d_out, B, ntiles);
}

// Round 5
// 259.252 us; speedup vs baseline: 1.8293x; 1.8293x over previous
//
#include <hip/hip_runtime.h>
#include <math.h>

// PillarAttentionClassifier — R6: R5 with the spill fixed.
// R5's __launch_bounds__(256,3) capped VGPRs at 84 < ~150 live (26 B-frags
// = 104 VGPRs alone) -> 520 MB scratch spill traffic (FETCH/WRITE counters).
// Back to (256,2) = R2's 256-VGPR budget. Kept from R5 (both bit-identical):
//   * x load software-pipelined one tile ahead.
//   * stage-2 A-frags (3x ds_read_b128 of repT) reused by stage-3.
//   * 16 tiles/block -> 2048 blocks.
// Datapath/LDS layout exactly R2 (absmax 0.0039 verified twice).

typedef _Float16 f16x8 __attribute__((ext_vector_type(8)));
typedef float    f32x4 __attribute__((ext_vector_type(4)));

#define EPS 1e-5f

__device__ __forceinline__ float rcp_fast(float v) { return __builtin_amdgcn_rcpf(v); }

__host__ __device__ constexpr unsigned long long packGS() {
    constexpr int gs[12] = {0,3,5,7,10,12,15,17,19,20,23,26};
    unsigned long long v = 0;
    for (int g = 0; g < 12; ++g) v |= (unsigned long long)gs[g] << (5*g);
    return v;
}
__host__ __device__ constexpr unsigned packGL() {
    constexpr int gl[12] = {3,2,2,3,2,3,2,2,1,3,3,3};
    unsigned v = 0;
    for (int g = 0; g < 12; ++g) v |= (unsigned)gl[g] << (2*g);
    return v;
}

__global__ __launch_bounds__(256, 2) void fused_kernel(
    const float* __restrict__ x,
    const float* __restrict__ We,  const float* __restrict__ be,
    const float* __restrict__ eg,  const float* __restrict__ ebt,
    const float* __restrict__ em,  const float* __restrict__ ev,
    const float* __restrict__ Wa,  const float* __restrict__ ba,
    const float* __restrict__ W1,  const float* __restrict__ b1,
    const float* __restrict__ g1,  const float* __restrict__ bb1,
    const float* __restrict__ m1,  const float* __restrict__ v1,
    const float* __restrict__ W2,  const float* __restrict__ b2,
    const float* __restrict__ g2,  const float* __restrict__ bb2,
    const float* __restrict__ m2,  const float* __restrict__ v2,
    const float* __restrict__ W3,  const float* __restrict__ b3,
    const float* __restrict__ g3,  const float* __restrict__ bb3,
    const float* __restrict__ m3,  const float* __restrict__ v3,
    const float* __restrict__ W4,  const float* __restrict__ b4,
    float* __restrict__ out, int B, int ntiles)
{
    // per-wave private LDS scratch: 8192 B each, 4 waves = 32 KiB (R2 layout)
    __shared__ __align__(16) char smem_raw[32768];
    const int lane = threadIdx.x & 63;
    const int wave = threadIdx.x >> 6;
    const int l15  = lane & 15;
    const int quad = lane >> 4;

    char* sw = smem_raw + wave * 8192;
    _Float16* repT = (_Float16*)(sw);          // [16][104] f16
    float*    wT   = (float*)   (sw + 3328);   // [16][17]  f32
    _Float16* h1T  = (_Float16*)(sw + 4416);   // [16][72]  f16
    _Float16* h2T  = (_Float16*)(sw + 6720);   // [16][40]  f16

    constexpr unsigned long long GS = packGS();
    constexpr unsigned GL = packGL();

    // ================= per-block prologue: B-frags + params (L2-resident) ========
    f16x8 Benc[6];
    #pragma unroll
    for (int t = 0; t < 6; ++t) {
        const int n = t*16 + l15;
        const int g = n >> 3, o = n & 7;
        const int gs = (int)((GS >> (5*g)) & 31);
        const int gl = (int)((GL >> (2*g)) & 3);
        #pragma unroll
        for (int j = 0; j < 8; ++j) {
            const int k  = quad*8 + j;
            const int ji = k - gs;
            float v = (ji >= 0 && ji < gl) ? We[(g*3 + ji)*8 + o] : 0.f;
            Benc[t][j] = (_Float16)v;
        }
    }
    f16x8 Bwa[3];
    #pragma unroll
    for (int s = 0; s < 3; ++s) {
        #pragma unroll
        for (int j = 0; j < 8; ++j) {
            const int k = s*32 + quad*8 + j;
            float v = (l15 < 12) ? Wa[k*12 + l15] : 0.f;
            Bwa[s][j] = (_Float16)v;
        }
    }
    f16x8 Bw1[12];
    #pragma unroll
    for (int t = 0; t < 4; ++t)
        #pragma unroll
        for (int s = 0; s < 3; ++s)
            #pragma unroll
            for (int j = 0; j < 8; ++j) {
                const int k = s*32 + quad*8 + j;
                Bw1[t*3 + s][j] = (_Float16)W1[k*64 + t*16 + l15];
            }
    f16x8 Bw2[4];
    #pragma unroll
    for (int t = 0; t < 2; ++t)
        #pragma unroll
        for (int s = 0; s < 2; ++s)
            #pragma unroll
            for (int j = 0; j < 8; ++j) {
                const int k = s*32 + quad*8 + j;
                Bw2[t*2 + s][j] = (_Float16)W2[k*32 + t*16 + l15];
            }
    f16x8 Bw3;
    #pragma unroll
    for (int j = 0; j < 8; ++j)
        Bw3[j] = (_Float16)W3[(quad*8 + j)*16 + l15];

    // per-lane params (indexed by output col n = lane&15 within each 16-block)
    float encB[6], encS[6], encT[6];
    #pragma unroll
    for (int t = 0; t < 6; ++t) {
        const int c = t*16 + l15;
        float s = eg[c] * rsqrtf(ev[c] + EPS);
        encS[t] = s; encT[t] = ebt[c] - em[c]*s; encB[t] = be[c];
    }
    const float baL = (l15 < 12) ? ba[l15] : -1e4f;   // pad cols -> softmax weight 0
    float b1L[4], s1L[4], t1L[4];
    #pragma unroll
    for (int t = 0; t < 4; ++t) {
        const int c = t*16 + l15;
        float s = g1[c] * rsqrtf(v1[c] + EPS);
        s1L[t] = s; t1L[t] = bb1[c] - m1[c]*s; b1L[t] = b1[c];
    }
    float b2L[2], s2L[2], t2L[2];
    #pragma unroll
    for (int t = 0; t < 2; ++t) {
        const int c = t*16 + l15;
        float s = g2[c] * rsqrtf(v2[c] + EPS);
        s2L[t] = s; t2L[t] = bb2[c] - m2[c]*s; b2L[t] = b2[c];
    }
    const float sv3 = g3[l15] * rsqrtf(v3[l15] + EPS);
    const float b3L = b3[l15], s3L = sv3, t3L = bb3[l15] - m3[l15]*sv3;
    const float w4L = W4[l15];
    const float b4v = b4[0];

    // ================= main loop: 16 tiles/block, 4/wave, x prefetched ===========
    const int tile0 = blockIdx.x * 16;
    int tile1 = tile0 + 16; if (tile1 > ntiles) tile1 = ntiles;

    auto load_x = [&](int t, float* d) {
        const int rb = t << 4;
        int xr = rb + l15; if (xr > B-1) xr = B-1;
        const float* xp = x + (size_t)xr*29 + (quad<<3);
        if (quad < 3) {
            #pragma unroll
            for (int j = 0; j < 8; ++j) d[j] = xp[j];
        } else {
            #pragma unroll
            for (int j = 0; j < 5; ++j) d[j] = xp[j];
            d[5] = d[6] = d[7] = 0.f;
        }
    };

    float xv[8];
    int tile = tile0 + wave;
    if (tile < tile1) load_x(tile, xv);

    for (; tile < tile1; tile += 4) {
        const int rowbase = tile << 4;

        // ---- prefetch next tile's x (overlaps with this tile's compute) ----
        float xn[8];
        {
            int nt = tile + 4;
            load_x(nt < tile1 ? nt : tile, xn);
        }

        // ---- x A-frag: A[m=l15][k=quad*8+j] ----
        f16x8 ax;
        #pragma unroll
        for (int j = 0; j < 8; ++j) ax[j] = (_Float16)xv[j];

        // ---- stage 1: rep[16][96] = BNaff(relu(x @ Wenc + be)) ----
        #pragma unroll
        for (int t = 0; t < 6; ++t) {
            f32x4 c = { encB[t], encB[t], encB[t], encB[t] };
            c = __builtin_amdgcn_mfma_f32_16x16x32_f16(ax, Benc[t], c, 0, 0, 0);
            #pragma unroll
            for (int r = 0; r < 4; ++r) {
                float v = fmaf(fmaxf(c[r], 0.f), encS[t], encT[t]);
                repT[(quad*4 + r)*104 + t*16 + l15] = (_Float16)v;
            }
        }

        // ---- read rep A-frags once; reused by stage 2 AND stage 3 ----
        f16x8 aS[3];
        #pragma unroll
        for (int s = 0; s < 3; ++s)
            aS[s] = *(const f16x8*)(repT + l15*104 + s*32 + quad*8);

        // ---- stage 2: logits = rep @ Wa + ba ; softmax over 12 (per quad) ----
        f32x4 c2 = { baL, baL, baL, baL };
        #pragma unroll
        for (int s = 0; s < 3; ++s)
            c2 = __builtin_amdgcn_mfma_f32_16x16x32_f16(aS[s], Bwa[s], c2, 0, 0, 0);
        #pragma unroll
        for (int r = 0; r < 4; ++r) {
            float v = c2[r];
            float mx = v;
            mx = fmaxf(mx, __shfl_xor(mx, 1));
            mx = fmaxf(mx, __shfl_xor(mx, 2));
            mx = fmaxf(mx, __shfl_xor(mx, 4));
            mx = fmaxf(mx, __shfl_xor(mx, 8));
            float e = __expf(v - mx);
            float sm = e;
            sm += __shfl_xor(sm, 1);
            sm += __shfl_xor(sm, 2);
            sm += __shfl_xor(sm, 4);
            sm += __shfl_xor(sm, 8);
            wT[(quad*4 + r)*17 + l15] = e * rcp_fast(sm);
        }

        // ---- stage 3: h1 = BNaff(relu((rep .* w_group) @ W1 + b1)) ----
        // A-frag k-range s*32+quad*8..+7 -> group g = s*4+quad constant per frag
        f32x4 c3[4];
        #pragma unroll
        for (int t = 0; t < 4; ++t) c3[t] = { b1L[t], b1L[t], b1L[t], b1L[t] };
        #pragma unroll
        for (int s = 0; s < 3; ++s) {
            _Float16 wh = (_Float16)wT[l15*17 + s*4 + quad];
            f16x8 aw;
            #pragma unroll
            for (int j = 0; j < 8; ++j) aw[j] = aS[s][j] * wh;
            #pragma unroll
            for (int t = 0; t < 4; ++t)
                c3[t] = __builtin_amdgcn_mfma_f32_16x16x32_f16(aw, Bw1[t*3 + s], c3[t], 0, 0, 0);
        }
        #pragma unroll
        for (int t = 0; t < 4; ++t)
            #pragma unroll
            for (int r = 0; r < 4; ++r) {
                float v = fmaf(fmaxf(c3[t][r], 0.f), s1L[t], t1L[t]);
                h1T[(quad*4 + r)*72 + t*16 + l15] = (_Float16)v;
            }

        // ---- stage 4: h2 = BNaff(relu(h1 @ W2 + b2)) ----
        f32x4 c4[2];
        #pragma unroll
        for (int t = 0; t < 2; ++t) c4[t] = { b2L[t], b2L[t], b2L[t], b2L[t] };
        #pragma unroll
        for (int s = 0; s < 2; ++s) {
            f16x8 a = *(const f16x8*)(h1T + l15*72 + s*32 + quad*8);
            #pragma unroll
            for (int t = 0; t < 2; ++t)
                c4[t] = __builtin_amdgcn_mfma_f32_16x16x32_f16(a, Bw2[t*2 + s], c4[t], 0, 0, 0);
        }
        #pragma unroll
        for (int t = 0; t < 2; ++t)
            #pragma unroll
            for (int r = 0; r < 4; ++r) {
                float v = fmaf(fmaxf(c4[t][r], 0.f), s2L[t], t2L[t]);
                h2T[(quad*4 + r)*40 + t*16 + l15] = (_Float16)v;
            }

        // ---- stage 5: h3 = BNaff(relu(h2 @ W3 + b3)) (stays in regs) ----
        f32x4 c5 = { b3L, b3L, b3L, b3L };
        {
            f16x8 a = *(const f16x8*)(h2T + l15*40 + quad*8);
            c5 = __builtin_amdgcn_mfma_f32_16x16x32_f16(a, Bw3, c5, 0, 0, 0);
        }

        // ---- stage 6: z = h3 @ W4 + b4 ; sigmoid ; store ----
        float z[4];
        #pragma unroll
        for (int r = 0; r < 4; ++r) {
            float v = fmaf(fmaxf(c5[r], 0.f), s3L, t3L);
            float p = v * w4L;
            p += __shfl_xor(p, 1);
            p += __shfl_xor(p, 2);
            p += __shfl_xor(p, 4);
            p += __shfl_xor(p, 8);
            z[r] = p;
        }
        float zi = (l15 == 0) ? z[0] : (l15 == 1) ? z[1] : (l15 == 2) ? z[2] : z[3];
        if (l15 < 4) {
            int row = rowbase + quad*4 + l15;
            if (row < B)
                out[row] = rcp_fast(1.f + __expf(-(zi + b4v)));
        }

        // ---- rotate prefetch ----
        #pragma unroll
        for (int j = 0; j < 8; ++j) xv[j] = xn[j];
    }
}

extern "C" void kernel_launch(void* const* d_in, const int* in_sizes, int n_in,
                              void* d_out, int out_size, void* d_ws, size_t ws_size,
                              hipStream_t stream)
{
    const float* x   = (const float*)d_in[0];
    const float* We  = (const float*)d_in[1];
    const float* be  = (const float*)d_in[2];
    const float* eg  = (const float*)d_in[3];
    const float* ebt = (const float*)d_in[4];
    const float* em  = (const float*)d_in[5];
    const float* ev  = (const float*)d_in[6];
    const float* Wa  = (const float*)d_in[7];
    const float* ba  = (const float*)d_in[8];
    const float* W1  = (const float*)d_in[9];
    const float* b1  = (const float*)d_in[10];
    const float* g1  = (const float*)d_in[11];
    const float* bb1 = (const float*)d_in[12];
    const float* m1  = (const float*)d_in[13];
    const float* v1  = (const float*)d_in[14];
    const float* W2  = (const float*)d_in[15];
    const float* b2  = (const float*)d_in[16];
    const float* g2  = (const float*)d_in[17];
    const float* bb2 = (const float*)d_in[18];
    const float* m2  = (const float*)d_in[19];
    const float* v2  = (const float*)d_in[20];
    const float* W3  = (const float*)d_in[21];
    const float* b3  = (const float*)d_in[22];
    const float* g3  = (const float*)d_in[23];
    const float* bb3 = (const float*)d_in[24];
    const float* m3  = (const float*)d_in[25];
    const float* v3  = (const float*)d_in[26];
    const float* W4  = (const float*)d_in[27];
    const float* b4  = (const float*)d_in[28];

    const int B = in_sizes[0] / 29;
    const int ntiles = (B + 15) / 16;
    const int blocks = (ntiles + 15) / 16;   // 16 tiles per block (4 per wave)

    fused_kernel<<<blocks, 256, 0, stream>>>(
        x, We, be, eg, ebt, em, ev, Wa, ba,
        W1, b1, g1, bb1, m1, v1,
        W2, b2, g2, bb2, m2, v2,
        W3, b3, g3, bb3, m3, v3,
        W4, b4, (float*)d_out, B, ntiles);
}

// Round 6
// 253.754 us; speedup vs baseline: 1.8689x; 1.0217x over previous
//
#include <hip/hip_runtime.h>
#include <math.h>

// PillarAttentionClassifier — R7: kill the scratch arrays.
// R6's 88 MB WRITE_SIZE = xv[8]/xn[8] demoted to scratch (lambda took float*,
// address-taken arrays defeat SROA -> per-tile scalar stores+reloads through
// the memory pipe). Fix: x tile is an ext_vector f32x8 (SSA register value)
// returned by value; tail cols handled with per-element selects. No address
// taken anywhere in the loop. Datapath/LDS layout exactly R2 (absmax 0.0039).
// Kept: x prefetch one tile ahead; stage-2 A-frags reused by stage-3;
// 16 tiles/block; __launch_bounds__(256,2).

typedef _Float16 f16x8 __attribute__((ext_vector_type(8)));
typedef float    f32x4 __attribute__((ext_vector_type(4)));
typedef float    f32x8 __attribute__((ext_vector_type(8)));

#define EPS 1e-5f

__device__ __forceinline__ float rcp_fast(float v) { return __builtin_amdgcn_rcpf(v); }

__host__ __device__ constexpr unsigned long long packGS() {
    constexpr int gs[12] = {0,3,5,7,10,12,15,17,19,20,23,26};
    unsigned long long v = 0;
    for (int g = 0; g < 12; ++g) v |= (unsigned long long)gs[g] << (5*g);
    return v;
}
__host__ __device__ constexpr unsigned packGL() {
    constexpr int gl[12] = {3,2,2,3,2,3,2,2,1,3,3,3};
    unsigned v = 0;
    for (int g = 0; g < 12; ++g) v |= (unsigned)gl[g] << (2*g);
    return v;
}

__global__ __launch_bounds__(256, 2) void fused_kernel(
    const float* __restrict__ x,
    const float* __restrict__ We,  const float* __restrict__ be,
    const float* __restrict__ eg,  const float* __restrict__ ebt,
    const float* __restrict__ em,  const float* __restrict__ ev,
    const float* __restrict__ Wa,  const float* __restrict__ ba,
    const float* __restrict__ W1,  const float* __restrict__ b1,
    const float* __restrict__ g1,  const float* __restrict__ bb1,
    const float* __restrict__ m1,  const float* __restrict__ v1,
    const float* __restrict__ W2,  const float* __restrict__ b2,
    const float* __restrict__ g2,  const float* __restrict__ bb2,
    const float* __restrict__ m2,  const float* __restrict__ v2,
    const float* __restrict__ W3,  const float* __restrict__ b3,
    const float* __restrict__ g3,  const float* __restrict__ bb3,
    const float* __restrict__ m3,  const float* __restrict__ v3,
    const float* __restrict__ W4,  const float* __restrict__ b4,
    float* __restrict__ out, int B, int ntiles)
{
    // per-wave private LDS scratch: 8192 B each, 4 waves = 32 KiB (R2 layout)
    __shared__ __align__(16) char smem_raw[32768];
    const int lane = threadIdx.x & 63;
    const int wave = threadIdx.x >> 6;
    const int l15  = lane & 15;
    const int quad = lane >> 4;

    char* sw = smem_raw + wave * 8192;
    _Float16* repT = (_Float16*)(sw);          // [16][104] f16
    float*    wT   = (float*)   (sw + 3328);   // [16][17]  f32
    _Float16* h1T  = (_Float16*)(sw + 4416);   // [16][72]  f16
    _Float16* h2T  = (_Float16*)(sw + 6720);   // [16][40]  f16

    constexpr unsigned long long GS = packGS();
    constexpr unsigned GL = packGL();

    // ================= per-block prologue: B-frags + params (L2-resident) ========
    f16x8 Benc[6];
    #pragma unroll
    for (int t = 0; t < 6; ++t) {
        const int n = t*16 + l15;
        const int g = n >> 3, o = n & 7;
        const int gs = (int)((GS >> (5*g)) & 31);
        const int gl = (int)((GL >> (2*g)) & 3);
        #pragma unroll
        for (int j = 0; j < 8; ++j) {
            const int k  = quad*8 + j;
            const int ji = k - gs;
            float v = (ji >= 0 && ji < gl) ? We[(g*3 + ji)*8 + o] : 0.f;
            Benc[t][j] = (_Float16)v;
        }
    }
    f16x8 Bwa[3];
    #pragma unroll
    for (int s = 0; s < 3; ++s) {
        #pragma unroll
        for (int j = 0; j < 8; ++j) {
            const int k = s*32 + quad*8 + j;
            float v = (l15 < 12) ? Wa[k*12 + l15] : 0.f;
            Bwa[s][j] = (_Float16)v;
        }
    }
    f16x8 Bw1[12];
    #pragma unroll
    for (int t = 0; t < 4; ++t)
        #pragma unroll
        for (int s = 0; s < 3; ++s)
            #pragma unroll
            for (int j = 0; j < 8; ++j) {
                const int k = s*32 + quad*8 + j;
                Bw1[t*3 + s][j] = (_Float16)W1[k*64 + t*16 + l15];
            }
    f16x8 Bw2[4];
    #pragma unroll
    for (int t = 0; t < 2; ++t)
        #pragma unroll
        for (int s = 0; s < 2; ++s)
            #pragma unroll
            for (int j = 0; j < 8; ++j) {
                const int k = s*32 + quad*8 + j;
                Bw2[t*2 + s][j] = (_Float16)W2[k*32 + t*16 + l15];
            }
    f16x8 Bw3;
    #pragma unroll
    for (int j = 0; j < 8; ++j)
        Bw3[j] = (_Float16)W3[(quad*8 + j)*16 + l15];

    // per-lane params (indexed by output col n = lane&15 within each 16-block)
    float encB[6], encS[6], encT[6];
    #pragma unroll
    for (int t = 0; t < 6; ++t) {
        const int c = t*16 + l15;
        float s = eg[c] * rsqrtf(ev[c] + EPS);
        encS[t] = s; encT[t] = ebt[c] - em[c]*s; encB[t] = be[c];
    }
    const float baL = (l15 < 12) ? ba[l15] : -1e4f;   // pad cols -> softmax weight 0
    float b1L[4], s1L[4], t1L[4];
    #pragma unroll
    for (int t = 0; t < 4; ++t) {
        const int c = t*16 + l15;
        float s = g1[c] * rsqrtf(v1[c] + EPS);
        s1L[t] = s; t1L[t] = bb1[c] - m1[c]*s; b1L[t] = b1[c];
    }
    float b2L[2], s2L[2], t2L[2];
    #pragma unroll
    for (int t = 0; t < 2; ++t) {
        const int c = t*16 + l15;
        float s = g2[c] * rsqrtf(v2[c] + EPS);
        s2L[t] = s; t2L[t] = bb2[c] - m2[c]*s; b2L[t] = b2[c];
    }
    const float sv3 = g3[l15] * rsqrtf(v3[l15] + EPS);
    const float b3L = b3[l15], s3L = sv3, t3L = bb3[l15] - m3[l15]*sv3;
    const float w4L = W4[l15];
    const float b4v = b4[0];

    // ================= main loop: 16 tiles/block, 4/wave, x prefetched ===========
    const int tile0 = blockIdx.x * 16;
    int tile1 = tile0 + 16; if (tile1 > ntiles) tile1 = ntiles;

    // x tile as an SSA vector value — never touches memory.
    auto load_x8 = [&](int t) -> f32x8 {
        int xr = (t << 4) + l15; if (xr > B-1) xr = B-1;
        const float* xp = x + (size_t)xr*29;
        const int base = quad << 3;
        f32x8 d;
        #pragma unroll
        for (int j = 0; j < 8; ++j) {
            const int col = base + j;
            d[j] = (col < 29) ? xp[col] : 0.f;
        }
        return d;
    };

    f32x8 xv = {0,0,0,0,0,0,0,0};
    int tile = tile0 + wave;
    if (tile < tile1) xv = load_x8(tile);

    for (; tile < tile1; tile += 4) {
        const int rowbase = tile << 4;

        // ---- prefetch next tile's x (overlaps with this tile's compute) ----
        const int nt = tile + 4;
        f32x8 xn = load_x8(nt < tile1 ? nt : tile);

        // ---- x A-frag: A[m=l15][k=quad*8+j] ----
        f16x8 ax;
        #pragma unroll
        for (int j = 0; j < 8; ++j) ax[j] = (_Float16)xv[j];

        // ---- stage 1: rep[16][96] = BNaff(relu(x @ Wenc + be)) ----
        #pragma unroll
        for (int t = 0; t < 6; ++t) {
            f32x4 c = { encB[t], encB[t], encB[t], encB[t] };
            c = __builtin_amdgcn_mfma_f32_16x16x32_f16(ax, Benc[t], c, 0, 0, 0);
            #pragma unroll
            for (int r = 0; r < 4; ++r) {
                float v = fmaf(fmaxf(c[r], 0.f), encS[t], encT[t]);
                repT[(quad*4 + r)*104 + t*16 + l15] = (_Float16)v;
            }
        }

        // ---- read rep A-frags once; reused by stage 2 AND stage 3 ----
        f16x8 aS[3];
        #pragma unroll
        for (int s = 0; s < 3; ++s)
            aS[s] = *(const f16x8*)(repT + l15*104 + s*32 + quad*8);

        // ---- stage 2: logits = rep @ Wa + ba ; softmax over 12 (per quad) ----
        f32x4 c2 = { baL, baL, baL, baL };
        #pragma unroll
        for (int s = 0; s < 3; ++s)
            c2 = __builtin_amdgcn_mfma_f32_16x16x32_f16(aS[s], Bwa[s], c2, 0, 0, 0);
        #pragma unroll
        for (int r = 0; r < 4; ++r) {
            float v = c2[r];
            float mx = v;
            mx = fmaxf(mx, __shfl_xor(mx, 1));
            mx = fmaxf(mx, __shfl_xor(mx, 2));
            mx = fmaxf(mx, __shfl_xor(mx, 4));
            mx = fmaxf(mx, __shfl_xor(mx, 8));
            float e = __expf(v - mx);
            float sm = e;
            sm += __shfl_xor(sm, 1);
            sm += __shfl_xor(sm, 2);
            sm += __shfl_xor(sm, 4);
            sm += __shfl_xor(sm, 8);
            wT[(quad*4 + r)*17 + l15] = e * rcp_fast(sm);
        }

        // ---- stage 3: h1 = BNaff(relu((rep .* w_group) @ W1 + b1)) ----
        // A-frag k-range s*32+quad*8..+7 -> group g = s*4+quad constant per frag
        f32x4 c3[4];
        #pragma unroll
        for (int t = 0; t < 4; ++t) c3[t] = { b1L[t], b1L[t], b1L[t], b1L[t] };
        #pragma unroll
        for (int s = 0; s < 3; ++s) {
            _Float16 wh = (_Float16)wT[l15*17 + s*4 + quad];
            f16x8 aw;
            #pragma unroll
            for (int j = 0; j < 8; ++j) aw[j] = aS[s][j] * wh;
            #pragma unroll
            for (int t = 0; t < 4; ++t)
                c3[t] = __builtin_amdgcn_mfma_f32_16x16x32_f16(aw, Bw1[t*3 + s], c3[t], 0, 0, 0);
        }
        #pragma unroll
        for (int t = 0; t < 4; ++t)
            #pragma unroll
            for (int r = 0; r < 4; ++r) {
                float v = fmaf(fmaxf(c3[t][r], 0.f), s1L[t], t1L[t]);
                h1T[(quad*4 + r)*72 + t*16 + l15] = (_Float16)v;
            }

        // ---- stage 4: h2 = BNaff(relu(h1 @ W2 + b2)) ----
        f32x4 c4[2];
        #pragma unroll
        for (int t = 0; t < 2; ++t) c4[t] = { b2L[t], b2L[t], b2L[t], b2L[t] };
        #pragma unroll
        for (int s = 0; s < 2; ++s) {
            f16x8 a = *(const f16x8*)(h1T + l15*72 + s*32 + quad*8);
            #pragma unroll
            for (int t = 0; t < 2; ++t)
                c4[t] = __builtin_amdgcn_mfma_f32_16x16x32_f16(a, Bw2[t*2 + s], c4[t], 0, 0, 0);
        }
        #pragma unroll
        for (int t = 0; t < 2; ++t)
            #pragma unroll
            for (int r = 0; r < 4; ++r) {
                float v = fmaf(fmaxf(c4[t][r], 0.f), s2L[t], t2L[t]);
                h2T[(quad*4 + r)*40 + t*16 + l15] = (_Float16)v;
            }

        // ---- stage 5: h3 = BNaff(relu(h2 @ W3 + b3)) (stays in regs) ----
        f32x4 c5 = { b3L, b3L, b3L, b3L };
        {
            f16x8 a = *(const f16x8*)(h2T + l15*40 + quad*8);
            c5 = __builtin_amdgcn_mfma_f32_16x16x32_f16(a, Bw3, c5, 0, 0, 0);
        }

        // ---- stage 6: z = h3 @ W4 + b4 ; sigmoid ; store ----
        float z[4];
        #pragma unroll
        for (int r = 0; r < 4; ++r) {
            float v = fmaf(fmaxf(c5[r], 0.f), s3L, t3L);
            float p = v * w4L;
            p += __shfl_xor(p, 1);
            p += __shfl_xor(p, 2);
            p += __shfl_xor(p, 4);
            p += __shfl_xor(p, 8);
            z[r] = p;
        }
        float zi = (l15 == 0) ? z[0] : (l15 == 1) ? z[1] : (l15 == 2) ? z[2] : z[3];
        if (l15 < 4) {
            int row = rowbase + quad*4 + l15;
            if (row < B)
                out[row] = rcp_fast(1.f + __expf(-(zi + b4v)));
        }

        // ---- rotate prefetch (register move) ----
        xv = xn;
    }
}

extern "C" void kernel_launch(void* const* d_in, const int* in_sizes, int n_in,
                              void* d_out, int out_size, void* d_ws, size_t ws_size,
                              hipStream_t stream)
{
    const float* x   = (const float*)d_in[0];
    const float* We  = (const float*)d_in[1];
    const float* be  = (const float*)d_in[2];
    const float* eg  = (const float*)d_in[3];
    const float* ebt = (const float*)d_in[4];
    const float* em  = (const float*)d_in[5];
    const float* ev  = (const float*)d_in[6];
    const float* Wa  = (const float*)d_in[7];
    const float* ba  = (const float*)d_in[8];
    const float* W1  = (const float*)d_in[9];
    const float* b1  = (const float*)d_in[10];
    const float* g1  = (const float*)d_in[11];
    const float* bb1 = (const float*)d_in[12];
    const float* m1  = (const float*)d_in[13];
    const float* v1  = (const float*)d_in[14];
    const float* W2  = (const float*)d_in[15];
    const float* b2  = (const float*)d_in[16];
    const float* g2  = (const float*)d_in[17];
    const float* bb2 = (const float*)d_in[18];
    const float* m2  = (const float*)d_in[19];
    const float* v2  = (const float*)d_in[20];
    const float* W3  = (const float*)d_in[21];
    const float* b3  = (const float*)d_in[22];
    const float* g3  = (const float*)d_in[23];
    const float* bb3 = (const float*)d_in[24];
    const float* m3  = (const float*)d_in[25];
    const float* v3  = (const float*)d_in[26];
    const float* W4  = (const float*)d_in[27];
    const float* b4  = (const float*)d_in[28];

    const int B = in_sizes[0] / 29;
    const int ntiles = (B + 15) / 16;
    const int blocks = (ntiles + 15) / 16;   // 16 tiles per block (4 per wave)

    fused_kernel<<<blocks, 256, 0, stream>>>(
        x, We, be, eg, ebt, em, ev, Wa, ba,
        W1, b1, g1, bb1, m1, v1,
        W2, b2, g2, bb2, m2, v2,
        W3, b3, g3, bb3, m3, v3,
        W4, b4, (float*)d_out, B, ntiles);
}

// Round 8
// 219.552 us; speedup vs baseline: 2.1601x; 1.1558x over previous
//
#include <hip/hip_runtime.h>
#include <math.h>

// PillarAttentionClassifier — R8b: resubmit of R8 (container infra flake).
// R6/R7 spilled ~10-16 regs/lane in-loop (WRITE_SIZE 74-88 MB vs 2 MB true
// output): live set ~145 > the 128-reg 4-waves/SIMD boundary the backend's
// occupancy heuristic targets. VGPR_Count=128 exactly = the tell.
// Fix: amdgpu_waves_per_eu(2,2) pins target occupancy to 2 waves/EU ->
// 256-reg budget -> no spill. Also back to 32 tiles/block (R2's prologue
// amortization; 16-tile blocks doubled weight refetch: FETCH 30->46 MB).
// Kept (verified correct in R6/R7): f32x8 SSA x-tile + one-tile prefetch;
// stage-2 A-frags reused by stage-3. Datapath exactly R2 (absmax 0.0039).

typedef _Float16 f16x8 __attribute__((ext_vector_type(8)));
typedef float    f32x4 __attribute__((ext_vector_type(4)));
typedef float    f32x8 __attribute__((ext_vector_type(8)));

#define EPS 1e-5f

__device__ __forceinline__ float rcp_fast(float v) { return __builtin_amdgcn_rcpf(v); }

__host__ __device__ constexpr unsigned long long packGS() {
    constexpr int gs[12] = {0,3,5,7,10,12,15,17,19,20,23,26};
    unsigned long long v = 0;
    for (int g = 0; g < 12; ++g) v |= (unsigned long long)gs[g] << (5*g);
    return v;
}
__host__ __device__ constexpr unsigned packGL() {
    constexpr int gl[12] = {3,2,2,3,2,3,2,2,1,3,3,3};
    unsigned v = 0;
    for (int g = 0; g < 12; ++g) v |= (unsigned)gl[g] << (2*g);
    return v;
}

__global__ __launch_bounds__(256)
__attribute__((amdgpu_waves_per_eu(2, 2)))
void fused_kernel(
    const float* __restrict__ x,
    const float* __restrict__ We,  const float* __restrict__ be,
    const float* __restrict__ eg,  const float* __restrict__ ebt,
    const float* __restrict__ em,  const float* __restrict__ ev,
    const float* __restrict__ Wa,  const float* __restrict__ ba,
    const float* __restrict__ W1,  const float* __restrict__ b1,
    const float* __restrict__ g1,  const float* __restrict__ bb1,
    const float* __restrict__ m1,  const float* __restrict__ v1,
    const float* __restrict__ W2,  const float* __restrict__ b2,
    const float* __restrict__ g2,  const float* __restrict__ bb2,
    const float* __restrict__ m2,  const float* __restrict__ v2,
    const float* __restrict__ W3,  const float* __restrict__ b3,
    const float* __restrict__ g3,  const float* __restrict__ bb3,
    const float* __restrict__ m3,  const float* __restrict__ v3,
    const float* __restrict__ W4,  const float* __restrict__ b4,
    float* __restrict__ out, int B, int ntiles)
{
    // per-wave private LDS scratch: 8192 B each, 4 waves = 32 KiB (R2 layout)
    __shared__ __align__(16) char smem_raw[32768];
    const int lane = threadIdx.x & 63;
    const int wave = threadIdx.x >> 6;
    const int l15  = lane & 15;
    const int quad = lane >> 4;

    char* sw = smem_raw + wave * 8192;
    _Float16* repT = (_Float16*)(sw);          // [16][104] f16
    float*    wT   = (float*)   (sw + 3328);   // [16][17]  f32
    _Float16* h1T  = (_Float16*)(sw + 4416);   // [16][72]  f16
    _Float16* h2T  = (_Float16*)(sw + 6720);   // [16][40]  f16

    constexpr unsigned long long GS = packGS();
    constexpr unsigned GL = packGL();

    // ================= per-block prologue: B-frags + params (L2-resident) ========
    f16x8 Benc[6];
    #pragma unroll
    for (int t = 0; t < 6; ++t) {
        const int n = t*16 + l15;
        const int g = n >> 3, o = n & 7;
        const int gs = (int)((GS >> (5*g)) & 31);
        const int gl = (int)((GL >> (2*g)) & 3);
        #pragma unroll
        for (int j = 0; j < 8; ++j) {
            const int k  = quad*8 + j;
            const int ji = k - gs;
            float v = (ji >= 0 && ji < gl) ? We[(g*3 + ji)*8 + o] : 0.f;
            Benc[t][j] = (_Float16)v;
        }
    }
    f16x8 Bwa[3];
    #pragma unroll
    for (int s = 0; s < 3; ++s) {
        #pragma unroll
        for (int j = 0; j < 8; ++j) {
            const int k = s*32 + quad*8 + j;
            float v = (l15 < 12) ? Wa[k*12 + l15] : 0.f;
            Bwa[s][j] = (_Float16)v;
        }
    }
    f16x8 Bw1[12];
    #pragma unroll
    for (int t = 0; t < 4; ++t)
        #pragma unroll
        for (int s = 0; s < 3; ++s)
            #pragma unroll
            for (int j = 0; j < 8; ++j) {
                const int k = s*32 + quad*8 + j;
                Bw1[t*3 + s][j] = (_Float16)W1[k*64 + t*16 + l15];
            }
    f16x8 Bw2[4];
    #pragma unroll
    for (int t = 0; t < 2; ++t)
        #pragma unroll
        for (int s = 0; s < 2; ++s)
            #pragma unroll
            for (int j = 0; j < 8; ++j) {
                const int k = s*32 + quad*8 + j;
                Bw2[t*2 + s][j] = (_Float16)W2[k*32 + t*16 + l15];
            }
    f16x8 Bw3;
    #pragma unroll
    for (int j = 0; j < 8; ++j)
        Bw3[j] = (_Float16)W3[(quad*8 + j)*16 + l15];

    // per-lane params (indexed by output col n = lane&15 within each 16-block)
    float encB[6], encS[6], encT[6];
    #pragma unroll
    for (int t = 0; t < 6; ++t) {
        const int c = t*16 + l15;
        float s = eg[c] * rsqrtf(ev[c] + EPS);
        encS[t] = s; encT[t] = ebt[c] - em[c]*s; encB[t] = be[c];
    }
    const float baL = (l15 < 12) ? ba[l15] : -1e4f;   // pad cols -> softmax weight 0
    float b1L[4], s1L[4], t1L[4];
    #pragma unroll
    for (int t = 0; t < 4; ++t) {
        const int c = t*16 + l15;
        float s = g1[c] * rsqrtf(v1[c] + EPS);
        s1L[t] = s; t1L[t] = bb1[c] - m1[c]*s; b1L[t] = b1[c];
    }
    float b2L[2], s2L[2], t2L[2];
    #pragma unroll
    for (int t = 0; t < 2; ++t) {
        const int c = t*16 + l15;
        float s = g2[c] * rsqrtf(v2[c] + EPS);
        s2L[t] = s; t2L[t] = bb2[c] - m2[c]*s; b2L[t] = b2[c];
    }
    const float sv3 = g3[l15] * rsqrtf(v3[l15] + EPS);
    const float b3L = b3[l15], s3L = sv3, t3L = bb3[l15] - m3[l15]*sv3;
    const float w4L = W4[l15];
    const float b4v = b4[0];

    // ================= main loop: 32 tiles/block, 8/wave, x prefetched ===========
    const int tile0 = blockIdx.x * 32;
    int tile1 = tile0 + 32; if (tile1 > ntiles) tile1 = ntiles;

    // x tile as an SSA vector value — never touches memory.
    auto load_x8 = [&](int t) -> f32x8 {
        int xr = (t << 4) + l15; if (xr > B-1) xr = B-1;
        const float* xp = x + (size_t)xr*29;
        const int base = quad << 3;
        f32x8 d;
        #pragma unroll
        for (int j = 0; j < 8; ++j) {
            const int col = base + j;
            d[j] = (col < 29) ? xp[col] : 0.f;
        }
        return d;
    };

    f32x8 xv = {0,0,0,0,0,0,0,0};
    int tile = tile0 + wave;
    if (tile < tile1) xv = load_x8(tile);

    for (; tile < tile1; tile += 4) {
        const int rowbase = tile << 4;

        // ---- prefetch next tile's x (overlaps with this tile's compute) ----
        const int nt = tile + 4;
        f32x8 xn = load_x8(nt < tile1 ? nt : tile);

        // ---- x A-frag: A[m=l15][k=quad*8+j] ----
        f16x8 ax;
        #pragma unroll
        for (int j = 0; j < 8; ++j) ax[j] = (_Float16)xv[j];

        // ---- stage 1: rep[16][96] = BNaff(relu(x @ Wenc + be)) ----
        #pragma unroll
        for (int t = 0; t < 6; ++t) {
            f32x4 c = { encB[t], encB[t], encB[t], encB[t] };
            c = __builtin_amdgcn_mfma_f32_16x16x32_f16(ax, Benc[t], c, 0, 0, 0);
            #pragma unroll
            for (int r = 0; r < 4; ++r) {
                float v = fmaf(fmaxf(c[r], 0.f), encS[t], encT[t]);
                repT[(quad*4 + r)*104 + t*16 + l15] = (_Float16)v;
            }
        }

        // ---- read rep A-frags once; reused by stage 2 AND stage 3 ----
        f16x8 aS[3];
        #pragma unroll
        for (int s = 0; s < 3; ++s)
            aS[s] = *(const f16x8*)(repT + l15*104 + s*32 + quad*8);

        // ---- stage 2: logits = rep @ Wa + ba ; softmax over 12 (per quad) ----
        f32x4 c2 = { baL, baL, baL, baL };
        #pragma unroll
        for (int s = 0; s < 3; ++s)
            c2 = __builtin_amdgcn_mfma_f32_16x16x32_f16(aS[s], Bwa[s], c2, 0, 0, 0);
        #pragma unroll
        for (int r = 0; r < 4; ++r) {
            float v = c2[r];
            float mx = v;
            mx = fmaxf(mx, __shfl_xor(mx, 1));
            mx = fmaxf(mx, __shfl_xor(mx, 2));
            mx = fmaxf(mx, __shfl_xor(mx, 4));
            mx = fmaxf(mx, __shfl_xor(mx, 8));
            float e = __expf(v - mx);
            float sm = e;
            sm += __shfl_xor(sm, 1);
            sm += __shfl_xor(sm, 2);
            sm += __shfl_xor(sm, 4);
            sm += __shfl_xor(sm, 8);
            wT[(quad*4 + r)*17 + l15] = e * rcp_fast(sm);
        }

        // ---- stage 3: h1 = BNaff(relu((rep .* w_group) @ W1 + b1)) ----
        // A-frag k-range s*32+quad*8..+7 -> group g = s*4+quad constant per frag
        f32x4 c3[4];
        #pragma unroll
        for (int t = 0; t < 4; ++t) c3[t] = { b1L[t], b1L[t], b1L[t], b1L[t] };
        #pragma unroll
        for (int s = 0; s < 3; ++s) {
            _Float16 wh = (_Float16)wT[l15*17 + s*4 + quad];
            f16x8 aw;
            #pragma unroll
            for (int j = 0; j < 8; ++j) aw[j] = aS[s][j] * wh;
            #pragma unroll
            for (int t = 0; t < 4; ++t)
                c3[t] = __builtin_amdgcn_mfma_f32_16x16x32_f16(aw, Bw1[t*3 + s], c3[t], 0, 0, 0);
        }
        #pragma unroll
        for (int t = 0; t < 4; ++t)
            #pragma unroll
            for (int r = 0; r < 4; ++r) {
                float v = fmaf(fmaxf(c3[t][r], 0.f), s1L[t], t1L[t]);
                h1T[(quad*4 + r)*72 + t*16 + l15] = (_Float16)v;
            }

        // ---- stage 4: h2 = BNaff(relu(h1 @ W2 + b2)) ----
        f32x4 c4[2];
        #pragma unroll
        for (int t = 0; t < 2; ++t) c4[t] = { b2L[t], b2L[t], b2L[t], b2L[t] };
        #pragma unroll
        for (int s = 0; s < 2; ++s) {
            f16x8 a = *(const f16x8*)(h1T + l15*72 + s*32 + quad*8);
            #pragma unroll
            for (int t = 0; t < 2; ++t)
                c4[t] = __builtin_amdgcn_mfma_f32_16x16x32_f16(a, Bw2[t*2 + s], c4[t], 0, 0, 0);
        }
        #pragma unroll
        for (int t = 0; t < 2; ++t)
            #pragma unroll
            for (int r = 0; r < 4; ++r) {
                float v = fmaf(fmaxf(c4[t][r], 0.f), s2L[t], t2L[t]);
                h2T[(quad*4 + r)*40 + t*16 + l15] = (_Float16)v;
            }

        // ---- stage 5: h3 = BNaff(relu(h2 @ W3 + b3)) (stays in regs) ----
        f32x4 c5 = { b3L, b3L, b3L, b3L };
        {
            f16x8 a = *(const f16x8*)(h2T + l15*40 + quad*8);
            c5 = __builtin_amdgcn_mfma_f32_16x16x32_f16(a, Bw3, c5, 0, 0, 0);
        }

        // ---- stage 6: z = h3 @ W4 + b4 ; sigmoid ; store ----
        float z[4];
        #pragma unroll
        for (int r = 0; r < 4; ++r) {
            float v = fmaf(fmaxf(c5[r], 0.f), s3L, t3L);
            float p = v * w4L;
            p += __shfl_xor(p, 1);
            p += __shfl_xor(p, 2);
            p += __shfl_xor(p, 4);
            p += __shfl_xor(p, 8);
            z[r] = p;
        }
        float zi = (l15 == 0) ? z[0] : (l15 == 1) ? z[1] : (l15 == 2) ? z[2] : z[3];
        if (l15 < 4) {
            int row = rowbase + quad*4 + l15;
            if (row < B)
                out[row] = rcp_fast(1.f + __expf(-(zi + b4v)));
        }

        // ---- rotate prefetch (register move) ----
        xv = xn;
    }
}

extern "C" void kernel_launch(void* const* d_in, const int* in_sizes, int n_in,
                              void* d_out, int out_size, void* d_ws, size_t ws_size,
                              hipStream_t stream)
{
    const float* x   = (const float*)d_in[0];
    const float* We  = (const float*)d_in[1];
    const float* be  = (const float*)d_in[2];
    const float* eg  = (const float*)d_in[3];
    const float* ebt = (const float*)d_in[4];
    const float* em  = (const float*)d_in[5];
    const float* ev  = (const float*)d_in[6];
    const float* Wa  = (const float*)d_in[7];
    const float* ba  = (const float*)d_in[8];
    const float* W1  = (const float*)d_in[9];
    const float* b1  = (const float*)d_in[10];
    const float* g1  = (const float*)d_in[11];
    const float* bb1 = (const float*)d_in[12];
    const float* m1  = (const float*)d_in[13];
    const float* v1  = (const float*)d_in[14];
    const float* W2  = (const float*)d_in[15];
    const float* b2  = (const float*)d_in[16];
    const float* g2  = (const float*)d_in[17];
    const float* bb2 = (const float*)d_in[18];
    const float* m2  = (const float*)d_in[19];
    const float* v2  = (const float*)d_in[20];
    const float* W3  = (const float*)d_in[21];
    const float* b3  = (const float*)d_in[22];
    const float* g3  = (const float*)d_in[23];
    const float* bb3 = (const float*)d_in[24];
    const float* m3  = (const float*)d_in[25];
    const float* v3  = (const float*)d_in[26];
    const float* W4  = (const float*)d_in[27];
    const float* b4  = (const float*)d_in[28];

    const int B = in_sizes[0] / 29;
    const int ntiles = (B + 15) / 16;
    const int blocks = (ntiles + 31) / 32;   // 32 tiles per block (8 per wave)

    fused_kernel<<<blocks, 256, 0, stream>>>(
        x, We, be, eg, ebt, em, ev, Wa, ba,
        W1, b1, g1, bb1, m1, v1,
        W2, b2, g2, bb2, m2, v2,
        W3, b3, g3, bb3, m3, v3,
        W4, b4, (float*)d_out, B, ntiles);
}

// Round 9
// 207.626 us; speedup vs baseline: 2.2841x; 1.0574x over previous
//
#include <hip/hip_runtime.h>
#include <math.h>

// PillarAttentionClassifier — R9: fit the live set under the 128-reg pin.
// Evidence chain: R6/R7/R8b all pinned VGPR_Count=128; WRITE_SIZE scaled with
// BLOCK count (74.6MB@2048 -> 38.9MB@1024) => prologue spill of ~37 regs
// (= the Bw1 set), reloaded from L2/L3 every tile in stage 3 — why R8b (100us)
// lost to R2 (80us). waves_per_eu didn't unpin (2 attempts).
// Fix: Bw1 (48 VGPRs) -> block-shared LDS W1T[64][104] f16 (13KiB; 208B rows:
// b128-aligned, bank-stride 52%32=20 -> 2-way = free). Stage-3 frags read JIT
// via 12x ds_read_b128/tile (not on the softmax critical path). x loaded as
// f16 directly (ax/axn: 8 regs vs 16; conversion point value-identical).
// Kept: prefetch one tile ahead; aS reuse (stage2->3); 32 tiles/block;
// __launch_bounds__(256,2). Datapath exactly R2 (absmax 0.0039).

typedef _Float16 f16x8 __attribute__((ext_vector_type(8)));
typedef float    f32x4 __attribute__((ext_vector_type(4)));

#define EPS 1e-5f

__device__ __forceinline__ float rcp_fast(float v) { return __builtin_amdgcn_rcpf(v); }

__host__ __device__ constexpr unsigned long long packGS() {
    constexpr int gs[12] = {0,3,5,7,10,12,15,17,19,20,23,26};
    unsigned long long v = 0;
    for (int g = 0; g < 12; ++g) v |= (unsigned long long)gs[g] << (5*g);
    return v;
}
__host__ __device__ constexpr unsigned packGL() {
    constexpr int gl[12] = {3,2,2,3,2,3,2,2,1,3,3,3};
    unsigned v = 0;
    for (int g = 0; g < 12; ++g) v |= (unsigned)gl[g] << (2*g);
    return v;
}

__global__ __launch_bounds__(256, 2) void fused_kernel(
    const float* __restrict__ x,
    const float* __restrict__ We,  const float* __restrict__ be,
    const float* __restrict__ eg,  const float* __restrict__ ebt,
    const float* __restrict__ em,  const float* __restrict__ ev,
    const float* __restrict__ Wa,  const float* __restrict__ ba,
    const float* __restrict__ W1,  const float* __restrict__ b1,
    const float* __restrict__ g1,  const float* __restrict__ bb1,
    const float* __restrict__ m1,  const float* __restrict__ v1,
    const float* __restrict__ W2,  const float* __restrict__ b2,
    const float* __restrict__ g2,  const float* __restrict__ bb2,
    const float* __restrict__ m2,  const float* __restrict__ v2,
    const float* __restrict__ W3,  const float* __restrict__ b3,
    const float* __restrict__ g3,  const float* __restrict__ bb3,
    const float* __restrict__ m3,  const float* __restrict__ v3,
    const float* __restrict__ W4,  const float* __restrict__ b4,
    float* __restrict__ out, int B, int ntiles)
{
    // [0,32768): per-wave scratch 4 x 8192 (R2 layout)
    // [32768, 46080): W1T[64][104] f16 — block-shared stage-3 weights
    __shared__ __align__(16) char smem_raw[46080];
    const int lane = threadIdx.x & 63;
    const int wave = threadIdx.x >> 6;
    const int l15  = lane & 15;
    const int quad = lane >> 4;

    char* sw = smem_raw + wave * 8192;
    _Float16* repT = (_Float16*)(sw);          // [16][104] f16
    float*    wT   = (float*)   (sw + 3328);   // [16][17]  f32
    _Float16* h1T  = (_Float16*)(sw + 4416);   // [16][72]  f16
    _Float16* h2T  = (_Float16*)(sw + 6720);   // [16][40]  f16
    _Float16* W1T  = (_Float16*)(smem_raw + 32768);   // [64][104] f16

    constexpr unsigned long long GS = packGS();
    constexpr unsigned GL = packGL();

    // ---- W1 -> LDS transposed: W1T[n][k] = W1[k][n]; rows padded to 104 ----
    for (int i = threadIdx.x; i < 96*64; i += 256) {
        const int k = i >> 6;          // 0..95
        const int n = i & 63;          // 0..63
        W1T[n*104 + k] = (_Float16)W1[k*64 + n];
    }

    // ================= per-block prologue: B-frags + params (L2-resident) ========
    f16x8 Benc[6];
    #pragma unroll
    for (int t = 0; t < 6; ++t) {
        const int n = t*16 + l15;
        const int g = n >> 3, o = n & 7;
        const int gs = (int)((GS >> (5*g)) & 31);
        const int gl = (int)((GL >> (2*g)) & 3);
        #pragma unroll
        for (int j = 0; j < 8; ++j) {
            const int k  = quad*8 + j;
            const int ji = k - gs;
            float v = (ji >= 0 && ji < gl) ? We[(g*3 + ji)*8 + o] : 0.f;
            Benc[t][j] = (_Float16)v;
        }
    }
    f16x8 Bwa[3];
    #pragma unroll
    for (int s = 0; s < 3; ++s) {
        #pragma unroll
        for (int j = 0; j < 8; ++j) {
            const int k = s*32 + quad*8 + j;
            float v = (l15 < 12) ? Wa[k*12 + l15] : 0.f;
            Bwa[s][j] = (_Float16)v;
        }
    }
    f16x8 Bw2[4];
    #pragma unroll
    for (int t = 0; t < 2; ++t)
        #pragma unroll
        for (int s = 0; s < 2; ++s)
            #pragma unroll
            for (int j = 0; j < 8; ++j) {
                const int k = s*32 + quad*8 + j;
                Bw2[t*2 + s][j] = (_Float16)W2[k*32 + t*16 + l15];
            }
    f16x8 Bw3;
    #pragma unroll
    for (int j = 0; j < 8; ++j)
        Bw3[j] = (_Float16)W3[(quad*8 + j)*16 + l15];

    // per-lane params (indexed by output col n = lane&15 within each 16-block)
    float encB[6], encS[6], encT[6];
    #pragma unroll
    for (int t = 0; t < 6; ++t) {
        const int c = t*16 + l15;
        float s = eg[c] * rsqrtf(ev[c] + EPS);
        encS[t] = s; encT[t] = ebt[c] - em[c]*s; encB[t] = be[c];
    }
    const float baL = (l15 < 12) ? ba[l15] : -1e4f;   // pad cols -> softmax weight 0
    float b1L[4], s1L[4], t1L[4];
    #pragma unroll
    for (int t = 0; t < 4; ++t) {
        const int c = t*16 + l15;
        float s = g1[c] * rsqrtf(v1[c] + EPS);
        s1L[t] = s; t1L[t] = bb1[c] - m1[c]*s; b1L[t] = b1[c];
    }
    float b2L[2], s2L[2], t2L[2];
    #pragma unroll
    for (int t = 0; t < 2; ++t) {
        const int c = t*16 + l15;
        float s = g2[c] * rsqrtf(v2[c] + EPS);
        s2L[t] = s; t2L[t] = bb2[c] - m2[c]*s; b2L[t] = b2[c];
    }
    const float sv3 = g3[l15] * rsqrtf(v3[l15] + EPS);
    const float b3L = b3[l15], s3L = sv3, t3L = bb3[l15] - m3[l15]*sv3;
    const float w4L = W4[l15];
    const float b4v = b4[0];

    __syncthreads();   // W1T visible to all waves (once per block)

    // ================= main loop: 32 tiles/block, 8/wave, x prefetched ===========
    const int tile0 = blockIdx.x * 32;
    int tile1 = tile0 + 32; if (tile1 > ntiles) tile1 = ntiles;

    // x tile loaded and converted to f16 immediately (SSA value, 4 regs).
    auto load_ax = [&](int t) -> f16x8 {
        int xr = (t << 4) + l15; if (xr > B-1) xr = B-1;
        const float* xp = x + (size_t)xr*29;
        const int base = quad << 3;
        f16x8 d;
        #pragma unroll
        for (int j = 0; j < 8; ++j) {
            const int col = base + j;
            d[j] = (col < 29) ? (_Float16)xp[col] : (_Float16)0.f;
        }
        return d;
    };

    f16x8 ax = {0,0,0,0,0,0,0,0};
    int tile = tile0 + wave;
    if (tile < tile1) ax = load_ax(tile);

    for (; tile < tile1; tile += 4) {
        const int rowbase = tile << 4;

        // ---- prefetch next tile's x (overlaps with this tile's compute) ----
        const int nt = tile + 4;
        f16x8 axn = load_ax(nt < tile1 ? nt : tile);

        // ---- stage 1: rep[16][96] = BNaff(relu(x @ Wenc + be)) ----
        #pragma unroll
        for (int t = 0; t < 6; ++t) {
            f32x4 c = { encB[t], encB[t], encB[t], encB[t] };
            c = __builtin_amdgcn_mfma_f32_16x16x32_f16(ax, Benc[t], c, 0, 0, 0);
            #pragma unroll
            for (int r = 0; r < 4; ++r) {
                float v = fmaf(fmaxf(c[r], 0.f), encS[t], encT[t]);
                repT[(quad*4 + r)*104 + t*16 + l15] = (_Float16)v;
            }
        }

        // ---- read rep A-frags once; reused by stage 2 AND stage 3 ----
        f16x8 aS[3];
        #pragma unroll
        for (int s = 0; s < 3; ++s)
            aS[s] = *(const f16x8*)(repT + l15*104 + s*32 + quad*8);

        // ---- stage 2: logits = rep @ Wa + ba ; softmax over 12 (per quad) ----
        f32x4 c2 = { baL, baL, baL, baL };
        #pragma unroll
        for (int s = 0; s < 3; ++s)
            c2 = __builtin_amdgcn_mfma_f32_16x16x32_f16(aS[s], Bwa[s], c2, 0, 0, 0);
        #pragma unroll
        for (int r = 0; r < 4; ++r) {
            float v = c2[r];
            float mx = v;
            mx = fmaxf(mx, __shfl_xor(mx, 1));
            mx = fmaxf(mx, __shfl_xor(mx, 2));
            mx = fmaxf(mx, __shfl_xor(mx, 4));
            mx = fmaxf(mx, __shfl_xor(mx, 8));
            float e = __expf(v - mx);
            float sm = e;
            sm += __shfl_xor(sm, 1);
            sm += __shfl_xor(sm, 2);
            sm += __shfl_xor(sm, 4);
            sm += __shfl_xor(sm, 8);
            wT[(quad*4 + r)*17 + l15] = e * rcp_fast(sm);
        }

        // ---- stage 3: h1 = BNaff(relu((rep .* w_group) @ W1 + b1)) ----
        // Bw1 frag (t,s) read JIT from W1T: row t*16+l15, halfwords s*32+quad*8..+7
        f32x4 c3[4];
        #pragma unroll
        for (int t = 0; t < 4; ++t) c3[t] = { b1L[t], b1L[t], b1L[t], b1L[t] };
        #pragma unroll
        for (int s = 0; s < 3; ++s) {
            _Float16 wh = (_Float16)wT[l15*17 + s*4 + quad];
            f16x8 aw;
            #pragma unroll
            for (int j = 0; j < 8; ++j) aw[j] = aS[s][j] * wh;
            #pragma unroll
            for (int t = 0; t < 4; ++t) {
                f16x8 bw1 = *(const f16x8*)(W1T + (t*16 + l15)*104 + s*32 + quad*8);
                c3[t] = __builtin_amdgcn_mfma_f32_16x16x32_f16(aw, bw1, c3[t], 0, 0, 0);
            }
        }
        #pragma unroll
        for (int t = 0; t < 4; ++t)
            #pragma unroll
            for (int r = 0; r < 4; ++r) {
                float v = fmaf(fmaxf(c3[t][r], 0.f), s1L[t], t1L[t]);
                h1T[(quad*4 + r)*72 + t*16 + l15] = (_Float16)v;
            }

        // ---- stage 4: h2 = BNaff(relu(h1 @ W2 + b2)) ----
        f32x4 c4[2];
        #pragma unroll
        for (int t = 0; t < 2; ++t) c4[t] = { b2L[t], b2L[t], b2L[t], b2L[t] };
        #pragma unroll
        for (int s = 0; s < 2; ++s) {
            f16x8 a = *(const f16x8*)(h1T + l15*72 + s*32 + quad*8);
            #pragma unroll
            for (int t = 0; t < 2; ++t)
                c4[t] = __builtin_amdgcn_mfma_f32_16x16x32_f16(a, Bw2[t*2 + s], c4[t], 0, 0, 0);
        }
        #pragma unroll
        for (int t = 0; t < 2; ++t)
            #pragma unroll
            for (int r = 0; r < 4; ++r) {
                float v = fmaf(fmaxf(c4[t][r], 0.f), s2L[t], t2L[t]);
                h2T[(quad*4 + r)*40 + t*16 + l15] = (_Float16)v;
            }

        // ---- stage 5: h3 = BNaff(relu(h2 @ W3 + b3)) (stays in regs) ----
        f32x4 c5 = { b3L, b3L, b3L, b3L };
        {
            f16x8 a = *(const f16x8*)(h2T + l15*40 + quad*8);
            c5 = __builtin_amdgcn_mfma_f32_16x16x32_f16(a, Bw3, c5, 0, 0, 0);
        }

        // ---- stage 6: z = h3 @ W4 + b4 ; sigmoid ; store ----
        float z[4];
        #pragma unroll
        for (int r = 0; r < 4; ++r) {
            float v = fmaf(fmaxf(c5[r], 0.f), s3L, t3L);
            float p = v * w4L;
            p += __shfl_xor(p, 1);
            p += __shfl_xor(p, 2);
            p += __shfl_xor(p, 4);
            p += __shfl_xor(p, 8);
            z[r] = p;
        }
        float zi = (l15 == 0) ? z[0] : (l15 == 1) ? z[1] : (l15 == 2) ? z[2] : z[3];
        if (l15 < 4) {
            int row = rowbase + quad*4 + l15;
            if (row < B)
                out[row] = rcp_fast(1.f + __expf(-(zi + b4v)));
        }

        // ---- rotate prefetch (register move) ----
        ax = axn;
    }
}

extern "C" void kernel_launch(void* const* d_in, const int* in_sizes, int n_in,
                              void* d_out, int out_size, void* d_ws, size_t ws_size,
                              hipStream_t stream)
{
    const float* x   = (const float*)d_in[0];
    const float* We  = (const float*)d_in[1];
    const float* be  = (const float*)d_in[2];
    const float* eg  = (const float*)d_in[3];
    const float* ebt = (const float*)d_in[4];
    const float* em  = (const float*)d_in[5];
    const float* ev  = (const float*)d_in[6];
    const float* Wa  = (const float*)d_in[7];
    const float* ba  = (const float*)d_in[8];
    const float* W1  = (const float*)d_in[9];
    const float* b1  = (const float*)d_in[10];
    const float* g1  = (const float*)d_in[11];
    const float* bb1 = (const float*)d_in[12];
    const float* m1  = (const float*)d_in[13];
    const float* v1  = (const float*)d_in[14];
    const float* W2  = (const float*)d_in[15];
    const float* b2  = (const float*)d_in[16];
    const float* g2  = (const float*)d_in[17];
    const float* bb2 = (const float*)d_in[18];
    const float* m2  = (const float*)d_in[19];
    const float* v2  = (const float*)d_in[20];
    const float* W3  = (const float*)d_in[21];
    const float* b3  = (const float*)d_in[22];
    const float* g3  = (const float*)d_in[23];
    const float* bb3 = (const float*)d_in[24];
    const float* m3  = (const float*)d_in[25];
    const float* v3  = (const float*)d_in[26];
    const float* W4  = (const float*)d_in[27];
    const float* b4  = (const float*)d_in[28];

    const int B = in_sizes[0] / 29;
    const int ntiles = (B + 15) / 16;
    const int blocks = (ntiles + 31) / 32;   // 32 tiles per block (8 per wave)

    fused_kernel<<<blocks, 256, 0, stream>>>(
        x, We, be, eg, ebt, em, ev, Wa, ba,
        W1, b1, g1, bb1, m1, v1,
        W2, b2, g2, bb2, m2, v2,
        W3, b3, g3, bb3, m3, v3,
        W4, b4, (float*)d_out, B, ntiles);
}